// Round 18
// baseline (247.476 us; speedup 1.0000x reference)
//
#include <hip/hip_runtime.h>

// Local context aggregation (DGCNN edge-conv style), MI355X.
// Pipeline (4 launches):
//   k_fp      : FUSED per-point pass: yG[n]=[F1|D1] (gather table, L2-fit/batch),
//               yC[n]=[Fc|Dc], xneg=-0.5|x|^2, bf16 hi table hb16[n][96], xT[n][96].
//   k_dist    : FUSED MFMA score + per-half top-24, bf16-only scoring (R17: 212->120us).
//               R18: dbuf+sched_barrier removed — kernel is VALU-bound (80% busy), TLP
//               covers the 4-load latency; the dbuf's +16 VGPR was re-triggering remat.
//   k_selstats: FUSED f64 re-rank (top-20 -> idx) + BN norm statistics.
//   k_out     : BN scale/shift inlined + gather + act + mean. R18: 512 thr, 64 lanes/row
//               (k-parity split, shfl_xor combine) — halves the serial gather chain.
// ws usage: ~40 MB fixed.

namespace {
constexpr int BB = 4;
constexpr int NN = 4096;
constexpr int KK = 20;
constexpr int CC = 96;      // 32 features x 3 dims
constexpr int OO = 32;
constexpr int PTS = BB * NN;
constexpr int LT = 12;      // per-class top list depth (class = 128 cands)
constexpr int TCAND = 24;   // per-half candidates kept
constexpr int NENT = 16 * LT;     // entries per row: 4 waves x 4 kl x 12 = 192
constexpr int NENT_PAD = 196;     // padded row stride (words)
}

using bf16x8 = __attribute__((ext_vector_type(8))) short;
using f32x4 = __attribute__((ext_vector_type(4))) float;

__device__ __forceinline__ unsigned short f2bf(float f) {
  unsigned u = __float_as_uint(f);
  return (unsigned short)((u + 0x7fff + ((u >> 16) & 1)) >> 16);
}
__device__ __forceinline__ unsigned umax32(unsigned a, unsigned b) { return a > b ? a : b; }
__device__ __forceinline__ unsigned med3u(unsigned a, unsigned b, unsigned c) {
  unsigned d;
  asm("v_med3_u32 %0, %1, %2, %3" : "=v"(d) : "v"(a), "v"(b), "v"(c));
  return d;
}

// ---------------- kernel 1: fused per-point pass ----------------
__global__ __launch_bounds__(256) void k_fp(
    const float* __restrict__ x, const float* __restrict__ Wf,
    const float* __restrict__ Wd,
    float* __restrict__ yG, float* __restrict__ yC, float* __restrict__ xneg,
    unsigned short* __restrict__ hb16, float* __restrict__ xT) {
  __shared__ float tile[CC][65];   // ~25 KB
  __shared__ float sW[4][32][32];  // 16 KB
  const int t = threadIdx.x;
  const int b = blockIdx.x >> 6;             // 64 blocks per batch
  const int n0 = (blockIdx.x & 63) * 64;
  for (int i = t; i < 2048; i += 256) {
    int o = i & 31, f = (i >> 5) & 31, which = i >> 10;
    const float* W = which ? Wd : Wf;
    float a1 = W[o * 64 + f], a2 = W[o * 64 + 32 + f];
    sW[which * 2 + 0][f][o] = a1;
    sW[which * 2 + 1][f][o] = a2 - a1;
  }
#pragma unroll
  for (int i = 0; i < 24; ++i) {
    int v = i * 256 + t;
    int c = v >> 6, nn = v & 63;
    tile[c][nn] = x[((size_t)b * CC + c) * NN + n0 + nn];
  }
  __syncthreads();

  // ---- bf16 hi table: hb16 rows [96 bf16], 12 x 16B chunks per row ----
#pragma unroll
  for (int i = 0; i < 3; ++i) {
    int v = i * 256 + t;                    // 0..767 over 64 rows x 12 chunks
    int row = v / 12, k8 = v % 12;
    int c0 = k8 * 8;
    unsigned hb[4];
#pragma unroll
    for (int j = 0; j < 4; ++j) {
      unsigned short l16 = f2bf(tile[c0 + 2 * j][row]);
      unsigned short h16 = f2bf(tile[c0 + 2 * j + 1][row]);
      hb[j] = (unsigned)l16 | ((unsigned)h16 << 16);
    }
    *(uint4*)(hb16 + (size_t)(b * NN + n0 + row) * 96 + k8 * 8) =
        make_uint4(hb[0], hb[1], hb[2], hb[3]);
  }
  // xT rows: 96 f32 contiguous per point
#pragma unroll
  for (int i = 0; i < 6; ++i) {
    int v = i * 256 + t;
    int row = v / 24, q = v % 24;
    float4 o4;
    o4.x = tile[q * 4 + 0][row]; o4.y = tile[q * 4 + 1][row];
    o4.z = tile[q * 4 + 2][row]; o4.w = tile[q * 4 + 3][row];
    *(float4*)(xT + (size_t)(b * NN + n0 + row) * CC + q * 4) = o4;
  }

  // ---- transforms: thread (o=t&31, pg=t>>5) handles 8 points ----
  const int o = t & 31, pg = t >> 5;
  for (int pp = 0; pp < 8; ++pp) {
    const int pl = pg * 8 + pp;              // point 0..63
    float aF1[3] = {0.f, 0.f, 0.f}, aFc[3] = {0.f, 0.f, 0.f};
    float aD1[3] = {0.f, 0.f, 0.f}, aDc[3] = {0.f, 0.f, 0.f};
#pragma unroll
    for (int f = 0; f < 32; ++f) {
      float w0 = sW[0][f][o], w1 = sW[1][f][o];
      float w2 = sW[2][f][o], w3 = sW[3][f][o];
#pragma unroll
      for (int dd = 0; dd < 3; ++dd) {
        float v = tile[f * 3 + dd][pl];
        aF1[dd] = fmaf(w0, v, aF1[dd]);
        aFc[dd] = fmaf(w1, v, aFc[dd]);
        aD1[dd] = fmaf(w2, v, aD1[dd]);
        aDc[dd] = fmaf(w3, v, aDc[dd]);
      }
    }
    const size_t pt = (size_t)(b * NN + n0 + pl) * 192 + o * 3;
#pragma unroll
    for (int dd = 0; dd < 3; ++dd) {
      yG[pt + dd] = aF1[dd]; yG[pt + 96 + dd] = aD1[dd];
      yC[pt + dd] = aFc[dd]; yC[pt + 96 + dd] = aDc[dd];
    }
  }
  // xneg: one thread per point
  if (t < 64) {
    float s = 0.f;
#pragma unroll 8
    for (int c = 0; c < CC; ++c) { float v = tile[c][t]; s = fmaf(v, v, s); }
    xneg[b * NN + n0 + t] = -0.5f * s;
  }
}

// ---------------- kernel 2: FUSED MFMA score + per-half top-24 ----------------
// 2048 blocks x 256 thr (4 waves). xcd=wg&7: b=xcd&3, half=xcd>>2. q=wg>>3 -> 16 rows.
// Wave w scans [half*2048 + w*512, +512): flat 32-step loop, direct loads (VALU-bound;
// TLP hides the 4-load latency). Score = hi_n.hi_m - 0.5|x_m|^2; f64 refine fixes order.
// key = monotone(score)[31:12] | class[10:7] | (127-local)[6:0]  (unique in block).
__global__ __launch_bounds__(256) void k_dist(
    const unsigned short* __restrict__ hl, const float* __restrict__ xneg,
    unsigned* __restrict__ candbuf) {
  __shared__ unsigned sEnt[16][NENT_PAD];
  const int t = threadIdx.x, lane = t & 63, w = t >> 6;
  const int wg = blockIdx.x;
  const int xcd = wg & 7;
  const int b = xcd & 3;
  const int half = xcd >> 2;
  const int nbase = (wg >> 3) << 4;          // 0..4080, step 16
  const int hoff = half * 2048;
  const int coff = hoff + w * 512;           // this wave's candidate range
  const unsigned short* hb = hl + (size_t)b * NN * 96;
  const int kl = lane >> 4, pr = lane & 15;
  const int cls = w * 4 + kl;                // 0..15
  const unsigned clsbase = (unsigned)(cls << 7);

  // resident operand-B fragments: the block's 16 query rows (col axis)
  bf16x8 rHf[3];
#pragma unroll
  for (int kb = 0; kb < 3; ++kb) {
    const unsigned short* p = hb + (size_t)(nbase + pr) * 96 + (kb * 4 + kl) * 8;
    rHf[kb] = *(const bf16x8*)p;
  }

  unsigned ls[LT];
#pragma unroll
  for (int j = 0; j < LT; ++j) ls[j] = 0u;   // 0 == -inf key

  // bases: candidate group idx (0..31) lives at pw + idx*1536 (shorts), xneg at px+idx*16
  const unsigned short* pw = hb + ((size_t)coff + pr) * 96 + (size_t)kl * 8;
  const float* px = xneg + (size_t)b * NN + coff + kl * 4;

#pragma unroll
  for (int idx = 0; idx < 32; ++idx) {
    const unsigned short* pc = pw + (size_t)idx * 1536;
    bf16x8 ch0 = *(const bf16x8*)(pc);
    bf16x8 ch1 = *(const bf16x8*)(pc + 32);
    bf16x8 ch2 = *(const bf16x8*)(pc + 64);
    f32x4 acc = *(const f32x4*)(px + idx * 16);   // -0.5*|xm|^2 preloaded
    acc = __builtin_amdgcn_mfma_f32_16x16x32_bf16(ch0, rHf[0], acc, 0, 0, 0);
    acc = __builtin_amdgcn_mfma_f32_16x16x32_bf16(ch1, rHf[1], acc, 0, 0, 0);
    acc = __builtin_amdgcn_mfma_f32_16x16x32_bf16(ch2, rHf[2], acc, 0, 0, 0);
    // C/D: col(lane&15)=query row; row((lane>>4)*4+r)=candidate offset.
    const unsigned tag = clsbase | (unsigned)(127 - idx * 4);
#pragma unroll
    for (int r = 0; r < 4; ++r) {
      unsigned sb = __float_as_uint(acc[r]);
      sb ^= ((unsigned)((int)sb >> 31)) | 0x80000000u;
      unsigned key = (sb & 0xFFFFF000u) | (tag - (unsigned)r);
      // in-place parallel sorted-desc insert via med3 (reads pre-insert state)
#pragma unroll
      for (int j = LT - 1; j >= 1; --j)
        ls[j] = med3u(ls[j - 1], ls[j], key);
      ls[0] = umax32(ls[0], key);
    }
  }
  // dump per-lane sorted key lists: row pr, entries [cls*12 .. +12)
  {
    unsigned* dst = &sEnt[pr][cls * LT];
    *(uint4*)(dst + 0) = make_uint4(ls[0], ls[1], ls[2], ls[3]);
    *(uint4*)(dst + 4) = make_uint4(ls[4], ls[5], ls[6], ls[7]);
    *(uint4*)(dst + 8) = make_uint4(ls[8], ls[9], ls[10], ls[11]);
  }
  __syncthreads();

  // rank-count merge: wave w handles rows w*4..w*4+3; lane owns entries {lane+64c}.
  // Keys unique -> ranks 0..191 a permutation -> all 24 candbuf slots written.
#pragma unroll
  for (int rr = 0; rr < 4; ++rr) {
    const int row = w * 4 + rr;
    unsigned mine[3]; int rk[3] = {0, 0, 0};
#pragma unroll
    for (int c = 0; c < 3; ++c) mine[c] = sEnt[row][lane + 64 * c];
    for (int i4 = 0; i4 < NENT / 4; ++i4) {
      uint4 e = *(const uint4*)&sEnt[row][i4 * 4];
#pragma unroll
      for (int c = 0; c < 3; ++c) {
        rk[c] += (e.x > mine[c]) ? 1 : 0;
        rk[c] += (e.y > mine[c]) ? 1 : 0;
        rk[c] += (e.z > mine[c]) ? 1 : 0;
        rk[c] += (e.w > mine[c]) ? 1 : 0;
      }
    }
#pragma unroll
    for (int c = 0; c < 3; ++c) {
      if (rk[c] < TCAND) {
        unsigned low = mine[c] & 0x7FFu;
        int kcls = (int)(low >> 7);
        int loc = 127 - (int)(low & 127u);
        unsigned id = (unsigned)(hoff + (kcls >> 2) * 512 + (loc >> 4) * 64 +
                                 ((loc >> 2) & 3) * 16 + (kcls & 3) * 4 + (loc & 3));
        candbuf[(size_t)(b * NN + nbase + row) * 48 + half * 24 + rk[c]] = id;
      }
    }
  }
}

// ---------------- kernel 3: FUSED exact f64 top-20 + BN statistics ----------------
// 512 thr = 8 waves, 8 rows/block, grid PTS/8, XCD-swizzled (b=blk&3).
__global__ __launch_bounds__(512) void k_selstats(
    const unsigned* __restrict__ candbuf, const float* __restrict__ xT,
    const float* __restrict__ yG, const float* __restrict__ yC,
    int* __restrict__ idxout, double* __restrict__ stats) {
  __shared__ int sTop[8][KK];
  __shared__ float rs1[8][32], rs2[8][32];
  const int t = threadIdx.x, lane = t & 63, w = t >> 6;
  const int b = blockIdx.x & 3;
  const int n = (blockIdx.x >> 2) * 8 + w;
  const int row = b * NN + n;
  const unsigned* cp = candbuf + (size_t)row * 48;
  const int hf = lane & 1;
  unsigned long long k0, k1; int c0, c1;
#pragma unroll
  for (int pass = 0; pass < 2; ++pass) {
    const int ci = pass * 24 + ((lane < 48) ? (lane >> 1) : 23);
    const int mycand = (int)cp[ci];
    const float* xm = xT + ((size_t)b * NN + mycand) * CC + hf * 48;
    const float* xr = xT + ((size_t)b * NN + n) * CC + hf * 48;
    double dot = 0.0, m2 = 0.0;
#pragma unroll 4
    for (int j = 0; j < 12; ++j) {
      float4 a = *(const float4*)&xm[j * 4];
      float4 q = *(const float4*)&xr[j * 4];
      dot = fma((double)q.x, (double)a.x, dot); m2 = fma((double)a.x, (double)a.x, m2);
      dot = fma((double)q.y, (double)a.y, dot); m2 = fma((double)a.y, (double)a.y, m2);
      dot = fma((double)q.z, (double)a.z, dot); m2 = fma((double)a.z, (double)a.z, m2);
      dot = fma((double)q.w, (double)a.w, dot); m2 = fma((double)a.w, (double)a.w, m2);
    }
    dot += __shfl_xor(dot, 1);
    m2 += __shfl_xor(m2, 1);
    double sc = 2.0 * dot - m2;
    unsigned long long bits = (unsigned long long)__double_as_longlong(sc);
    bits ^= ((unsigned long long)((long long)bits >> 63)) | 0x8000000000000000ull;
    unsigned long long key = (bits & ~0xFFFull) | (unsigned long long)(4095 - mycand);
    if (pass == 0) { k0 = key; c0 = mycand; } else { k1 = key; c1 = mycand; }
  }
  int r0c = 0, r1c = 0;
#pragma unroll
  for (int j = 0; j < 24; ++j) {
    unsigned long long a = __shfl(k0, j * 2);
    unsigned long long bb = __shfl(k1, j * 2);
    r0c += (a > k0) ? 1 : 0; r0c += (bb > k0) ? 1 : 0;
    r1c += (a > k1) ? 1 : 0; r1c += (bb > k1) ? 1 : 0;
  }
  if (lane < 48 && hf == 0) {
    if (r0c < KK) { idxout[(size_t)row * KK + r0c] = c0; sTop[w][r0c] = c0; }
    if (r1c < KK) { idxout[(size_t)row * KK + r1c] = c1; sTop[w][r1c] = c1; }
  }
  __builtin_amdgcn_wave_barrier();  // same-wave LDS write->read fence (compile-time)

  // ---- phase B: norm statistics for this row ----
  const int o = lane & 31, kh = lane >> 5;
  const size_t cb = (size_t)row * 192 + o * 3;
  const float pc0 = yC[cb], pc1 = yC[cb + 1], pc2 = yC[cb + 2];
  float s1 = 0.f, s2 = 0.f;
#pragma unroll
  for (int j = 0; j < 10; ++j) {
    int m = sTop[w][2 * j + kh];
    size_t a = ((size_t)b * NN + m) * 192 + o * 3;
    float p0 = yG[a] + pc0, p1 = yG[a + 1] + pc1, p2 = yG[a + 2] + pc2;
    float nr = sqrtf(p0 * p0 + p1 * p1 + p2 * p2) + 1e-6f;
    s1 += nr; s2 = fmaf(nr, nr, s2);
  }
  s1 += __shfl_xor(s1, 32);
  s2 += __shfl_xor(s2, 32);
  if (lane < 32) { rs1[w][o] = s1; rs2[w][o] = s2; }
  __syncthreads();
  if (t < 32) {
    float a1 = 0.f, a2 = 0.f;
#pragma unroll
    for (int ww = 0; ww < 8; ++ww) { a1 += rs1[ww][t]; a2 += rs2[ww][t]; }
    atomicAdd(&stats[t], (double)a1);
    atomicAdd(&stats[32 + t], (double)a2);
  }
}

// ---------------- kernel 4: gather + activation + mean over k (BN inlined) ----------------
// 512 thr = 8 waves, one row per wave; lane = (o=lane&31, kh=lane>>5): 10 neighbors each,
// shfl_xor(32) combine, kh==0 writes. XCD-swizzled (b=blk&3).
__global__ __launch_bounds__(512) void k_out(
    const float* __restrict__ yG, const float* __restrict__ yC,
    const int* __restrict__ idx, const double* __restrict__ stats,
    const float* __restrict__ gamma, const float* __restrict__ beta,
    float* __restrict__ out) {
  __shared__ float sS[64];
  const int t = threadIdx.x, lane = t & 63, w = t >> 6;
  if (t < 32) {
    const double M = (double)BB * NN * KK;
    double mean = stats[t] / M;
    double var = stats[32 + t] / M - mean * mean;
    double inv = 1.0 / sqrt(var + 1e-5);
    sS[t] = (float)((double)gamma[t] * inv);
    sS[32 + t] = (float)((double)beta[t] - mean * (double)gamma[t] * inv);
  }
  __syncthreads();
  const int b = blockIdx.x & 3;
  const int n = (blockIdx.x >> 2) * 8 + w;
  const int o = lane & 31, kh = lane >> 5;
  const size_t cb = (size_t)(b * NN + n) * 192 + o * 3;
  const float pc0 = yC[cb], pc1 = yC[cb + 1], pc2 = yC[cb + 2];
  const float dc0 = yC[cb + 96], dc1 = yC[cb + 97], dc2 = yC[cb + 98];
  const float sc = sS[o], sh = sS[32 + o];
  const int* ip = idx + (size_t)(b * NN + n) * KK;
  float a0 = 0.f, a1 = 0.f, a2 = 0.f;
#pragma unroll
  for (int j = 0; j < 10; ++j) {
    int m = ip[2 * j + kh];
    size_t a = (size_t)(b * NN + m) * 192 + o * 3;
    float p0 = yG[a] + pc0, p1 = yG[a + 1] + pc1, p2 = yG[a + 2] + pc2;
    float d0 = yG[a + 96] + dc0, d1 = yG[a + 97] + dc1, d2 = yG[a + 98] + dc2;
    float nr = sqrtf(p0 * p0 + p1 * p1 + p2 * p2) + 1e-6f;
    float f = (sc * nr + sh) / nr;
    p0 *= f; p1 *= f; p2 *= f;
    float dt = p0 * d0 + p1 * d1 + p2 * d2;
    float w8 = (dt >= 0.f) ? 0.f : 0.8f * dt / (d0 * d0 + d1 * d1 + d2 * d2 + 1e-6f);
    a0 += p0 - w8 * d0; a1 += p1 - w8 * d1; a2 += p2 - w8 * d2;
  }
  a0 += __shfl_xor(a0, 32);
  a1 += __shfl_xor(a1, 32);
  a2 += __shfl_xor(a2, 32);
  if (kh == 0) {
    const float inv = 1.f / (float)KK;
    const size_t ob = ((size_t)(b * OO + o) * 3) * NN + n;
    out[ob] = a0 * inv; out[ob + NN] = a1 * inv; out[ob + 2 * NN] = a2 * inv;
  }
}

extern "C" void kernel_launch(void* const* d_in, const int* in_sizes, int n_in,
                              void* d_out, int out_size, void* d_ws, size_t ws_size,
                              hipStream_t stream) {
  (void)in_sizes; (void)n_in; (void)out_size;
  const float* x = (const float*)d_in[0];
  const float* Wf = (const float*)d_in[1];
  const float* Wd = (const float*)d_in[2];
  const float* gamma = (const float*)d_in[3];
  const float* beta = (const float*)d_in[4];
  float* out = (float*)d_out;

  char* ws = (char*)d_ws;
  size_t off = 0;
  auto alloc = [&](size_t bytes) -> void* {
    void* p = ws + off;
    off += (bytes + 255) & ~(size_t)255;
    return p;
  };
  float* yG = (float*)alloc((size_t)PTS * 192 * 4);
  float* yC = (float*)alloc((size_t)PTS * 192 * 4);
  float* xneg = (float*)alloc((size_t)PTS * 4);
  int* idx   = (int*)alloc((size_t)PTS * KK * 4);
  double* stats = (double*)alloc(64 * 8);
  unsigned short* hb16 = (unsigned short*)alloc((size_t)PTS * 96 * 2);
  float* xT  = (float*)alloc((size_t)PTS * CC * 4);
  unsigned* candbuf = (unsigned*)alloc((size_t)PTS * 48 * 4);
  if (ws_size < off) return;

  hipMemsetAsync(stats, 0, 64 * 8, stream);
  k_fp<<<dim3(PTS / 64), dim3(256), 0, stream>>>(x, Wf, Wd, yG, yC, xneg, hb16, xT);
  k_dist<<<dim3(BB * NN / 16 * 2), dim3(256), 0, stream>>>(hb16, xneg, candbuf);
  k_selstats<<<dim3(PTS / 8), dim3(512), 0, stream>>>(candbuf, xT, yG, yC, idx, stats);
  k_out<<<dim3(PTS / 8), dim3(512), 0, stream>>>(yG, yC, idx, stats, gamma, beta, out);
}

// Round 19
// 239.750 us; speedup vs baseline: 1.0322x; 1.0322x over previous
//
#include <hip/hip_runtime.h>

// Local context aggregation (DGCNN edge-conv style), MI355X.
// Pipeline (4 launches):
//   k_fp      : FUSED per-point pass: yG[n]=[F1|D1] (gather table, L2-fit/batch),
//               yC[n]=[Fc|Dc], xneg=-0.5|x|^2, bf16 hi table hb16[n][96], xT[n][96].
//   k_dist    : FUSED MFMA score + per-half top-24, bf16-only scoring (R17: 120us).
//               R19: asm register pins — rHf pinned resident across the loop, prefetch
//               pinned at issue — the allocator's remat/reload bloat (VGPR 28-44 across
//               R17/R18, ~3x dynamic VALU) survives every indirect knob; opaque asm
//               makes the values non-rematerializable.
//   k_selstats: FUSED f64 re-rank (top-20 -> idx) + BN norm statistics.
//   k_out     : BN scale/shift inlined + gather + act + mean over k (R17 256-thr form;
//               R18's 512-thr split regressed ~8us).
// ws usage: ~40 MB fixed.

namespace {
constexpr int BB = 4;
constexpr int NN = 4096;
constexpr int KK = 20;
constexpr int CC = 96;      // 32 features x 3 dims
constexpr int OO = 32;
constexpr int PTS = BB * NN;
constexpr int LT = 12;      // per-class top list depth (class = 128 cands)
constexpr int TCAND = 24;   // per-half candidates kept
constexpr int NENT = 16 * LT;     // entries per row: 4 waves x 4 kl x 12 = 192
constexpr int NENT_PAD = 196;     // padded row stride (words)
}

using bf16x8 = __attribute__((ext_vector_type(8))) short;
using f32x4 = __attribute__((ext_vector_type(4))) float;

__device__ __forceinline__ unsigned short f2bf(float f) {
  unsigned u = __float_as_uint(f);
  return (unsigned short)((u + 0x7fff + ((u >> 16) & 1)) >> 16);
}
__device__ __forceinline__ unsigned umax32(unsigned a, unsigned b) { return a > b ? a : b; }
__device__ __forceinline__ unsigned med3u(unsigned a, unsigned b, unsigned c) {
  unsigned d;
  asm("v_med3_u32 %0, %1, %2, %3" : "=v"(d) : "v"(a), "v"(b), "v"(c));
  return d;
}
__device__ __forceinline__ void pin8(bf16x8& v) { asm volatile("" : "+v"(v)); }
__device__ __forceinline__ void pin4(f32x4& v) { asm volatile("" : "+v"(v)); }

// ---------------- kernel 1: fused per-point pass ----------------
__global__ __launch_bounds__(256) void k_fp(
    const float* __restrict__ x, const float* __restrict__ Wf,
    const float* __restrict__ Wd,
    float* __restrict__ yG, float* __restrict__ yC, float* __restrict__ xneg,
    unsigned short* __restrict__ hb16, float* __restrict__ xT) {
  __shared__ float tile[CC][65];   // ~25 KB
  __shared__ float sW[4][32][32];  // 16 KB
  const int t = threadIdx.x;
  const int b = blockIdx.x >> 6;             // 64 blocks per batch
  const int n0 = (blockIdx.x & 63) * 64;
  for (int i = t; i < 2048; i += 256) {
    int o = i & 31, f = (i >> 5) & 31, which = i >> 10;
    const float* W = which ? Wd : Wf;
    float a1 = W[o * 64 + f], a2 = W[o * 64 + 32 + f];
    sW[which * 2 + 0][f][o] = a1;
    sW[which * 2 + 1][f][o] = a2 - a1;
  }
#pragma unroll
  for (int i = 0; i < 24; ++i) {
    int v = i * 256 + t;
    int c = v >> 6, nn = v & 63;
    tile[c][nn] = x[((size_t)b * CC + c) * NN + n0 + nn];
  }
  __syncthreads();

  // ---- bf16 hi table: hb16 rows [96 bf16], 12 x 16B chunks per row ----
#pragma unroll
  for (int i = 0; i < 3; ++i) {
    int v = i * 256 + t;                    // 0..767 over 64 rows x 12 chunks
    int row = v / 12, k8 = v % 12;
    int c0 = k8 * 8;
    unsigned hb[4];
#pragma unroll
    for (int j = 0; j < 4; ++j) {
      unsigned short l16 = f2bf(tile[c0 + 2 * j][row]);
      unsigned short h16 = f2bf(tile[c0 + 2 * j + 1][row]);
      hb[j] = (unsigned)l16 | ((unsigned)h16 << 16);
    }
    *(uint4*)(hb16 + (size_t)(b * NN + n0 + row) * 96 + k8 * 8) =
        make_uint4(hb[0], hb[1], hb[2], hb[3]);
  }
  // xT rows: 96 f32 contiguous per point
#pragma unroll
  for (int i = 0; i < 6; ++i) {
    int v = i * 256 + t;
    int row = v / 24, q = v % 24;
    float4 o4;
    o4.x = tile[q * 4 + 0][row]; o4.y = tile[q * 4 + 1][row];
    o4.z = tile[q * 4 + 2][row]; o4.w = tile[q * 4 + 3][row];
    *(float4*)(xT + (size_t)(b * NN + n0 + row) * CC + q * 4) = o4;
  }

  // ---- transforms: thread (o=t&31, pg=t>>5) handles 8 points ----
  const int o = t & 31, pg = t >> 5;
  for (int pp = 0; pp < 8; ++pp) {
    const int pl = pg * 8 + pp;              // point 0..63
    float aF1[3] = {0.f, 0.f, 0.f}, aFc[3] = {0.f, 0.f, 0.f};
    float aD1[3] = {0.f, 0.f, 0.f}, aDc[3] = {0.f, 0.f, 0.f};
#pragma unroll
    for (int f = 0; f < 32; ++f) {
      float w0 = sW[0][f][o], w1 = sW[1][f][o];
      float w2 = sW[2][f][o], w3 = sW[3][f][o];
#pragma unroll
      for (int dd = 0; dd < 3; ++dd) {
        float v = tile[f * 3 + dd][pl];
        aF1[dd] = fmaf(w0, v, aF1[dd]);
        aFc[dd] = fmaf(w1, v, aFc[dd]);
        aD1[dd] = fmaf(w2, v, aD1[dd]);
        aDc[dd] = fmaf(w3, v, aDc[dd]);
      }
    }
    const size_t pt = (size_t)(b * NN + n0 + pl) * 192 + o * 3;
#pragma unroll
    for (int dd = 0; dd < 3; ++dd) {
      yG[pt + dd] = aF1[dd]; yG[pt + 96 + dd] = aD1[dd];
      yC[pt + dd] = aFc[dd]; yC[pt + 96 + dd] = aDc[dd];
    }
  }
  // xneg: one thread per point
  if (t < 64) {
    float s = 0.f;
#pragma unroll 8
    for (int c = 0; c < CC; ++c) { float v = tile[c][t]; s = fmaf(v, v, s); }
    xneg[b * NN + n0 + t] = -0.5f * s;
  }
}

// ---------------- kernel 2: FUSED MFMA score + per-half top-24 ----------------
// 2048 blocks x 256 thr (4 waves). xcd=wg&7: b=xcd&3, half=xcd>>2. q=wg>>3 -> 16 rows.
// Wave w scans [half*2048 + w*512, +512): flat 32-step loop, register double-buffer,
// bf16-only scoring (3 MFMA/tile, 4 loads/tile). asm pins stop remat/reload.
// key = monotone(score)[31:12] | class[10:7] | (127-local)[6:0]  (unique in block).
__global__ __launch_bounds__(256) void k_dist(
    const unsigned short* __restrict__ hl, const float* __restrict__ xneg,
    unsigned* __restrict__ candbuf) {
  __shared__ unsigned sEnt[16][NENT_PAD];
  const int t = threadIdx.x, lane = t & 63, w = t >> 6;
  const int wg = blockIdx.x;
  const int xcd = wg & 7;
  const int b = xcd & 3;
  const int half = xcd >> 2;
  const int nbase = (wg >> 3) << 4;          // 0..4080, step 16
  const int hoff = half * 2048;
  const int coff = hoff + w * 512;           // this wave's candidate range
  const unsigned short* hb = hl + (size_t)b * NN * 96;
  const int kl = lane >> 4, pr = lane & 15;
  const int cls = w * 4 + kl;                // 0..15
  const unsigned clsbase = (unsigned)(cls << 7);

  // resident operand-B fragments: the block's 16 query rows (col axis)
  bf16x8 rHf0, rHf1, rHf2;
  {
    const unsigned short* p = hb + (size_t)(nbase + pr) * 96 + (size_t)kl * 8;
    rHf0 = *(const bf16x8*)p;
    rHf1 = *(const bf16x8*)(p + 32);
    rHf2 = *(const bf16x8*)(p + 64);
  }
  // pin: non-rematerializable -> stays in VGPRs for the whole loop (no L2 reloads)
  pin8(rHf0); pin8(rHf1); pin8(rHf2);

  unsigned ls[LT];
#pragma unroll
  for (int j = 0; j < LT; ++j) ls[j] = 0u;   // 0 == -inf key

  // bases: candidate group idx (0..31) lives at pw + idx*1536 (shorts), xneg at px+idx*16
  const unsigned short* pw = hb + ((size_t)coff + pr) * 96 + (size_t)kl * 8;
  const float* px = xneg + (size_t)b * NN + coff + kl * 4;

  bf16x8 ch0, ch1, ch2;   // current fragment set
  f32x4 cxn;
  {
    ch0 = *(const bf16x8*)(pw);
    ch1 = *(const bf16x8*)(pw + 32);
    ch2 = *(const bf16x8*)(pw + 64);
    cxn = *(const f32x4*)(px);
  }
#pragma unroll
  for (int idx = 0; idx < 32; ++idx) {
    // prefetch next group (clamped tail)
    const int ni = (idx < 31) ? idx + 1 : 31;
    const unsigned short* pn = pw + (size_t)ni * 1536;
    bf16x8 nh0 = *(const bf16x8*)(pn);
    bf16x8 nh1 = *(const bf16x8*)(pn + 32);
    bf16x8 nh2 = *(const bf16x8*)(pn + 64);
    f32x4 nxn = *(const f32x4*)(px + ni * 16);
    // pin at issue: allocator cannot sink/reload these — true SW pipeline
    pin8(nh0); pin8(nh1); pin8(nh2); pin4(nxn);
    __builtin_amdgcn_sched_barrier(0);

    f32x4 acc = cxn;                          // -0.5*|xm|^2 preloaded
    acc = __builtin_amdgcn_mfma_f32_16x16x32_bf16(ch0, rHf0, acc, 0, 0, 0);
    acc = __builtin_amdgcn_mfma_f32_16x16x32_bf16(ch1, rHf1, acc, 0, 0, 0);
    acc = __builtin_amdgcn_mfma_f32_16x16x32_bf16(ch2, rHf2, acc, 0, 0, 0);
    // C/D: col(lane&15)=query row; row((lane>>4)*4+r)=candidate offset.
    const unsigned tag = clsbase | (unsigned)(127 - idx * 4);
#pragma unroll
    for (int r = 0; r < 4; ++r) {
      unsigned sb = __float_as_uint(acc[r]);
      sb ^= ((unsigned)((int)sb >> 31)) | 0x80000000u;
      unsigned key = (sb & 0xFFFFF000u) | (tag - (unsigned)r);
      // in-place parallel sorted-desc insert via med3 (reads pre-insert state)
#pragma unroll
      for (int j = LT - 1; j >= 1; --j)
        ls[j] = med3u(ls[j - 1], ls[j], key);
      ls[0] = umax32(ls[0], key);
    }
    // rotate buffers (free after full unroll: pure renaming)
    ch0 = nh0; ch1 = nh1; ch2 = nh2; cxn = nxn;
  }
  // dump per-lane sorted key lists: row pr, entries [cls*12 .. +12)
  {
    unsigned* dst = &sEnt[pr][cls * LT];
    *(uint4*)(dst + 0) = make_uint4(ls[0], ls[1], ls[2], ls[3]);
    *(uint4*)(dst + 4) = make_uint4(ls[4], ls[5], ls[6], ls[7]);
    *(uint4*)(dst + 8) = make_uint4(ls[8], ls[9], ls[10], ls[11]);
  }
  __syncthreads();

  // rank-count merge: wave w handles rows w*4..w*4+3; lane owns entries {lane+64c}.
  // Keys unique -> ranks 0..191 a permutation -> all 24 candbuf slots written.
#pragma unroll
  for (int rr = 0; rr < 4; ++rr) {
    const int row = w * 4 + rr;
    unsigned mine[3]; int rk[3] = {0, 0, 0};
#pragma unroll
    for (int c = 0; c < 3; ++c) mine[c] = sEnt[row][lane + 64 * c];
    for (int i4 = 0; i4 < NENT / 4; ++i4) {
      uint4 e = *(const uint4*)&sEnt[row][i4 * 4];
#pragma unroll
      for (int c = 0; c < 3; ++c) {
        rk[c] += (e.x > mine[c]) ? 1 : 0;
        rk[c] += (e.y > mine[c]) ? 1 : 0;
        rk[c] += (e.z > mine[c]) ? 1 : 0;
        rk[c] += (e.w > mine[c]) ? 1 : 0;
      }
    }
#pragma unroll
    for (int c = 0; c < 3; ++c) {
      if (rk[c] < TCAND) {
        unsigned low = mine[c] & 0x7FFu;
        int kcls = (int)(low >> 7);
        int loc = 127 - (int)(low & 127u);
        unsigned id = (unsigned)(hoff + (kcls >> 2) * 512 + (loc >> 4) * 64 +
                                 ((loc >> 2) & 3) * 16 + (kcls & 3) * 4 + (loc & 3));
        candbuf[(size_t)(b * NN + nbase + row) * 48 + half * 24 + rk[c]] = id;
      }
    }
  }
}

// ---------------- kernel 3: FUSED exact f64 top-20 + BN statistics ----------------
// 512 thr = 8 waves, 8 rows/block, grid PTS/8, XCD-swizzled (b=blk&3).
__global__ __launch_bounds__(512) void k_selstats(
    const unsigned* __restrict__ candbuf, const float* __restrict__ xT,
    const float* __restrict__ yG, const float* __restrict__ yC,
    int* __restrict__ idxout, double* __restrict__ stats) {
  __shared__ int sTop[8][KK];
  __shared__ float rs1[8][32], rs2[8][32];
  const int t = threadIdx.x, lane = t & 63, w = t >> 6;
  const int b = blockIdx.x & 3;
  const int n = (blockIdx.x >> 2) * 8 + w;
  const int row = b * NN + n;
  const unsigned* cp = candbuf + (size_t)row * 48;
  const int hf = lane & 1;
  unsigned long long k0, k1; int c0, c1;
#pragma unroll
  for (int pass = 0; pass < 2; ++pass) {
    const int ci = pass * 24 + ((lane < 48) ? (lane >> 1) : 23);
    const int mycand = (int)cp[ci];
    const float* xm = xT + ((size_t)b * NN + mycand) * CC + hf * 48;
    const float* xr = xT + ((size_t)b * NN + n) * CC + hf * 48;
    double dot = 0.0, m2 = 0.0;
#pragma unroll 4
    for (int j = 0; j < 12; ++j) {
      float4 a = *(const float4*)&xm[j * 4];
      float4 q = *(const float4*)&xr[j * 4];
      dot = fma((double)q.x, (double)a.x, dot); m2 = fma((double)a.x, (double)a.x, m2);
      dot = fma((double)q.y, (double)a.y, dot); m2 = fma((double)a.y, (double)a.y, m2);
      dot = fma((double)q.z, (double)a.z, dot); m2 = fma((double)a.z, (double)a.z, m2);
      dot = fma((double)q.w, (double)a.w, dot); m2 = fma((double)a.w, (double)a.w, m2);
    }
    dot += __shfl_xor(dot, 1);
    m2 += __shfl_xor(m2, 1);
    double sc = 2.0 * dot - m2;
    unsigned long long bits = (unsigned long long)__double_as_longlong(sc);
    bits ^= ((unsigned long long)((long long)bits >> 63)) | 0x8000000000000000ull;
    unsigned long long key = (bits & ~0xFFFull) | (unsigned long long)(4095 - mycand);
    if (pass == 0) { k0 = key; c0 = mycand; } else { k1 = key; c1 = mycand; }
  }
  int r0c = 0, r1c = 0;
#pragma unroll
  for (int j = 0; j < 24; ++j) {
    unsigned long long a = __shfl(k0, j * 2);
    unsigned long long bb = __shfl(k1, j * 2);
    r0c += (a > k0) ? 1 : 0; r0c += (bb > k0) ? 1 : 0;
    r1c += (a > k1) ? 1 : 0; r1c += (bb > k1) ? 1 : 0;
  }
  if (lane < 48 && hf == 0) {
    if (r0c < KK) { idxout[(size_t)row * KK + r0c] = c0; sTop[w][r0c] = c0; }
    if (r1c < KK) { idxout[(size_t)row * KK + r1c] = c1; sTop[w][r1c] = c1; }
  }
  __builtin_amdgcn_wave_barrier();  // same-wave LDS write->read fence (compile-time)

  // ---- phase B: norm statistics for this row ----
  const int o = lane & 31, kh = lane >> 5;
  const size_t cb = (size_t)row * 192 + o * 3;
  const float pc0 = yC[cb], pc1 = yC[cb + 1], pc2 = yC[cb + 2];
  float s1 = 0.f, s2 = 0.f;
#pragma unroll
  for (int j = 0; j < 10; ++j) {
    int m = sTop[w][2 * j + kh];
    size_t a = ((size_t)b * NN + m) * 192 + o * 3;
    float p0 = yG[a] + pc0, p1 = yG[a + 1] + pc1, p2 = yG[a + 2] + pc2;
    float nr = sqrtf(p0 * p0 + p1 * p1 + p2 * p2) + 1e-6f;
    s1 += nr; s2 = fmaf(nr, nr, s2);
  }
  s1 += __shfl_xor(s1, 32);
  s2 += __shfl_xor(s2, 32);
  if (lane < 32) { rs1[w][o] = s1; rs2[w][o] = s2; }
  __syncthreads();
  if (t < 32) {
    float a1 = 0.f, a2 = 0.f;
#pragma unroll
    for (int ww = 0; ww < 8; ++ww) { a1 += rs1[ww][t]; a2 += rs2[ww][t]; }
    atomicAdd(&stats[t], (double)a1);
    atomicAdd(&stats[32 + t], (double)a2);
  }
}

// ---------------- kernel 4: gather + activation + mean over k (BN inlined) ----------------
__global__ __launch_bounds__(256) void k_out(
    const float* __restrict__ yG, const float* __restrict__ yC,
    const int* __restrict__ idx, const double* __restrict__ stats,
    const float* __restrict__ gamma, const float* __restrict__ beta,
    float* __restrict__ out) {
  __shared__ float sS[64];
  const int t = threadIdx.x, o = t & 31, nl = t >> 5;
  if (t < 32) {
    const double M = (double)BB * NN * KK;
    double mean = stats[t] / M;
    double var = stats[32 + t] / M - mean * mean;
    double inv = 1.0 / sqrt(var + 1e-5);
    sS[t] = (float)((double)gamma[t] * inv);
    sS[32 + t] = (float)((double)beta[t] - mean * (double)gamma[t] * inv);
  }
  __syncthreads();
  const int b = blockIdx.x & 3;
  const int n = (blockIdx.x >> 2) * 8 + nl;
  const size_t cb = (size_t)(b * NN + n) * 192 + o * 3;
  const float pc0 = yC[cb], pc1 = yC[cb + 1], pc2 = yC[cb + 2];
  const float dc0 = yC[cb + 96], dc1 = yC[cb + 97], dc2 = yC[cb + 98];
  const float sc = sS[o], sh = sS[32 + o];
  const int* ip = idx + (size_t)(b * NN + n) * KK;
  float a0 = 0.f, a1 = 0.f, a2 = 0.f;
  for (int k = 0; k < KK; ++k) {
    int m = ip[k];
    size_t a = (size_t)(b * NN + m) * 192 + o * 3;
    float p0 = yG[a] + pc0, p1 = yG[a + 1] + pc1, p2 = yG[a + 2] + pc2;
    float d0 = yG[a + 96] + dc0, d1 = yG[a + 97] + dc1, d2 = yG[a + 98] + dc2;
    float nr = sqrtf(p0 * p0 + p1 * p1 + p2 * p2) + 1e-6f;
    float f = (sc * nr + sh) / nr;
    p0 *= f; p1 *= f; p2 *= f;
    float dt = p0 * d0 + p1 * d1 + p2 * d2;
    float w8 = (dt >= 0.f) ? 0.f : 0.8f * dt / (d0 * d0 + d1 * d1 + d2 * d2 + 1e-6f);
    a0 += p0 - w8 * d0; a1 += p1 - w8 * d1; a2 += p2 - w8 * d2;
  }
  const float inv = 1.f / (float)KK;
  const size_t ob = ((size_t)(b * OO + o) * 3) * NN + n;
  out[ob] = a0 * inv; out[ob + NN] = a1 * inv; out[ob + 2 * NN] = a2 * inv;
}

extern "C" void kernel_launch(void* const* d_in, const int* in_sizes, int n_in,
                              void* d_out, int out_size, void* d_ws, size_t ws_size,
                              hipStream_t stream) {
  (void)in_sizes; (void)n_in; (void)out_size;
  const float* x = (const float*)d_in[0];
  const float* Wf = (const float*)d_in[1];
  const float* Wd = (const float*)d_in[2];
  const float* gamma = (const float*)d_in[3];
  const float* beta = (const float*)d_in[4];
  float* out = (float*)d_out;

  char* ws = (char*)d_ws;
  size_t off = 0;
  auto alloc = [&](size_t bytes) -> void* {
    void* p = ws + off;
    off += (bytes + 255) & ~(size_t)255;
    return p;
  };
  float* yG = (float*)alloc((size_t)PTS * 192 * 4);
  float* yC = (float*)alloc((size_t)PTS * 192 * 4);
  float* xneg = (float*)alloc((size_t)PTS * 4);
  int* idx   = (int*)alloc((size_t)PTS * KK * 4);
  double* stats = (double*)alloc(64 * 8);
  unsigned short* hb16 = (unsigned short*)alloc((size_t)PTS * 96 * 2);
  float* xT  = (float*)alloc((size_t)PTS * CC * 4);
  unsigned* candbuf = (unsigned*)alloc((size_t)PTS * 48 * 4);
  if (ws_size < off) return;

  hipMemsetAsync(stats, 0, 64 * 8, stream);
  k_fp<<<dim3(PTS / 64), dim3(256), 0, stream>>>(x, Wf, Wd, yG, yC, xneg, hb16, xT);
  k_dist<<<dim3(BB * NN / 16 * 2), dim3(256), 0, stream>>>(hb16, xneg, candbuf);
  k_selstats<<<dim3(PTS / 8), dim3(512), 0, stream>>>(candbuf, xT, yG, yC, idx, stats);
  k_out<<<dim3(PTS / 8), dim3(256), 0, stream>>>(yG, yC, idx, stats, gamma, beta, out);
}

// Round 20
// 232.381 us; speedup vs baseline: 1.0650x; 1.0317x over previous
//
#include <hip/hip_runtime.h>

// Local context aggregation (DGCNN edge-conv style), MI355X.
// Pipeline (4 launches) — consolidated optimum (R17 reproduction):
//   k_fp      : FUSED per-point pass: yG[n]=[F1|D1] (gather table, L2-fit/batch),
//               yC[n]=[Fc|Dc], xneg=-0.5|x|^2, bf16 hi table hb16[n][96], xT[n][96].
//   k_dist    : FUSED MFMA score + per-half top-24, bf16-only coarse scoring
//               (R17: the decisive change — live set fits the allocator's preferred
//               64-reg tier, 212->120us; R18 dbuf-removal and R19 asm-pins both
//               regressed, so this keeps R17's exact dbuf+sched_barrier form).
//   k_selstats: FUSED f64 re-rank (top-20 -> idx) + BN norm statistics.
//   k_out     : BN scale/shift inlined + gather + directional leaky act + mean over k.
// ws usage: ~40 MB fixed.

namespace {
constexpr int BB = 4;
constexpr int NN = 4096;
constexpr int KK = 20;
constexpr int CC = 96;      // 32 features x 3 dims
constexpr int OO = 32;
constexpr int PTS = BB * NN;
constexpr int LT = 12;      // per-class top list depth (class = 128 cands)
constexpr int TCAND = 24;   // per-half candidates kept
constexpr int NENT = 16 * LT;     // entries per row: 4 waves x 4 kl x 12 = 192
constexpr int NENT_PAD = 196;     // padded row stride (words)
}

using bf16x8 = __attribute__((ext_vector_type(8))) short;
using f32x4 = __attribute__((ext_vector_type(4))) float;

__device__ __forceinline__ unsigned short f2bf(float f) {
  unsigned u = __float_as_uint(f);
  return (unsigned short)((u + 0x7fff + ((u >> 16) & 1)) >> 16);
}
__device__ __forceinline__ unsigned umax32(unsigned a, unsigned b) { return a > b ? a : b; }
__device__ __forceinline__ unsigned med3u(unsigned a, unsigned b, unsigned c) {
  unsigned d;
  asm("v_med3_u32 %0, %1, %2, %3" : "=v"(d) : "v"(a), "v"(b), "v"(c));
  return d;
}

// ---------------- kernel 1: fused per-point pass ----------------
__global__ __launch_bounds__(256) void k_fp(
    const float* __restrict__ x, const float* __restrict__ Wf,
    const float* __restrict__ Wd,
    float* __restrict__ yG, float* __restrict__ yC, float* __restrict__ xneg,
    unsigned short* __restrict__ hb16, float* __restrict__ xT) {
  __shared__ float tile[CC][65];   // ~25 KB
  __shared__ float sW[4][32][32];  // 16 KB
  const int t = threadIdx.x;
  const int b = blockIdx.x >> 6;             // 64 blocks per batch
  const int n0 = (blockIdx.x & 63) * 64;
  for (int i = t; i < 2048; i += 256) {
    int o = i & 31, f = (i >> 5) & 31, which = i >> 10;
    const float* W = which ? Wd : Wf;
    float a1 = W[o * 64 + f], a2 = W[o * 64 + 32 + f];
    sW[which * 2 + 0][f][o] = a1;
    sW[which * 2 + 1][f][o] = a2 - a1;
  }
#pragma unroll
  for (int i = 0; i < 24; ++i) {
    int v = i * 256 + t;
    int c = v >> 6, nn = v & 63;
    tile[c][nn] = x[((size_t)b * CC + c) * NN + n0 + nn];
  }
  __syncthreads();

  // ---- bf16 hi table: hb16 rows [96 bf16], 12 x 16B chunks per row ----
#pragma unroll
  for (int i = 0; i < 3; ++i) {
    int v = i * 256 + t;                    // 0..767 over 64 rows x 12 chunks
    int row = v / 12, k8 = v % 12;
    int c0 = k8 * 8;
    unsigned hb[4];
#pragma unroll
    for (int j = 0; j < 4; ++j) {
      unsigned short l16 = f2bf(tile[c0 + 2 * j][row]);
      unsigned short h16 = f2bf(tile[c0 + 2 * j + 1][row]);
      hb[j] = (unsigned)l16 | ((unsigned)h16 << 16);
    }
    *(uint4*)(hb16 + (size_t)(b * NN + n0 + row) * 96 + k8 * 8) =
        make_uint4(hb[0], hb[1], hb[2], hb[3]);
  }
  // xT rows: 96 f32 contiguous per point
#pragma unroll
  for (int i = 0; i < 6; ++i) {
    int v = i * 256 + t;
    int row = v / 24, q = v % 24;
    float4 o4;
    o4.x = tile[q * 4 + 0][row]; o4.y = tile[q * 4 + 1][row];
    o4.z = tile[q * 4 + 2][row]; o4.w = tile[q * 4 + 3][row];
    *(float4*)(xT + (size_t)(b * NN + n0 + row) * CC + q * 4) = o4;
  }

  // ---- transforms: thread (o=t&31, pg=t>>5) handles 8 points ----
  const int o = t & 31, pg = t >> 5;
  for (int pp = 0; pp < 8; ++pp) {
    const int pl = pg * 8 + pp;              // point 0..63
    float aF1[3] = {0.f, 0.f, 0.f}, aFc[3] = {0.f, 0.f, 0.f};
    float aD1[3] = {0.f, 0.f, 0.f}, aDc[3] = {0.f, 0.f, 0.f};
#pragma unroll
    for (int f = 0; f < 32; ++f) {
      float w0 = sW[0][f][o], w1 = sW[1][f][o];
      float w2 = sW[2][f][o], w3 = sW[3][f][o];
#pragma unroll
      for (int dd = 0; dd < 3; ++dd) {
        float v = tile[f * 3 + dd][pl];
        aF1[dd] = fmaf(w0, v, aF1[dd]);
        aFc[dd] = fmaf(w1, v, aFc[dd]);
        aD1[dd] = fmaf(w2, v, aD1[dd]);
        aDc[dd] = fmaf(w3, v, aDc[dd]);
      }
    }
    const size_t pt = (size_t)(b * NN + n0 + pl) * 192 + o * 3;
#pragma unroll
    for (int dd = 0; dd < 3; ++dd) {
      yG[pt + dd] = aF1[dd]; yG[pt + 96 + dd] = aD1[dd];
      yC[pt + dd] = aFc[dd]; yC[pt + 96 + dd] = aDc[dd];
    }
  }
  // xneg: one thread per point
  if (t < 64) {
    float s = 0.f;
#pragma unroll 8
    for (int c = 0; c < CC; ++c) { float v = tile[c][t]; s = fmaf(v, v, s); }
    xneg[b * NN + n0 + t] = -0.5f * s;
  }
}

// ---------------- kernel 2: FUSED MFMA score + per-half top-24 ----------------
// 2048 blocks x 256 thr (4 waves). xcd=wg&7: b=xcd&3, half=xcd>>2. q=wg>>3 -> 16 rows.
// Wave w scans [half*2048 + w*512, +512): flat 32-step loop, register double-buffer,
// bf16-only scoring (3 MFMA/tile, 4 loads/tile). Score = hi_n.hi_m - 0.5|x_m|^2;
// error ~0.03 ~= existing 20-bit key chop; f64 refine of the 48-union fixes order.
// key = monotone(score)[31:12] | class[10:7] | (127-local)[6:0]  (unique in block).
__global__ __launch_bounds__(256) void k_dist(
    const unsigned short* __restrict__ hl, const float* __restrict__ xneg,
    unsigned* __restrict__ candbuf) {
  __shared__ unsigned sEnt[16][NENT_PAD];
  const int t = threadIdx.x, lane = t & 63, w = t >> 6;
  const int wg = blockIdx.x;
  const int xcd = wg & 7;
  const int b = xcd & 3;
  const int half = xcd >> 2;
  const int nbase = (wg >> 3) << 4;          // 0..4080, step 16
  const int hoff = half * 2048;
  const int coff = hoff + w * 512;           // this wave's candidate range
  const unsigned short* hb = hl + (size_t)b * NN * 96;
  const int kl = lane >> 4, pr = lane & 15;
  const int cls = w * 4 + kl;                // 0..15
  const unsigned clsbase = (unsigned)(cls << 7);

  // resident operand-B fragments: the block's 16 query rows (col axis)
  bf16x8 rHf[3];
#pragma unroll
  for (int kb = 0; kb < 3; ++kb) {
    const unsigned short* p = hb + (size_t)(nbase + pr) * 96 + (kb * 4 + kl) * 8;
    rHf[kb] = *(const bf16x8*)p;
  }

  unsigned ls[LT];
#pragma unroll
  for (int j = 0; j < LT; ++j) ls[j] = 0u;   // 0 == -inf key

  // bases: candidate group idx (0..31) lives at pw + idx*1536 (shorts), xneg at px+idx*16
  const unsigned short* pw = hb + ((size_t)coff + pr) * 96 + (size_t)kl * 8;
  const float* px = xneg + (size_t)b * NN + coff + kl * 4;

  bf16x8 ch0, ch1, ch2;   // current fragment set
  f32x4 cxn;
  {
    ch0 = *(const bf16x8*)(pw);
    ch1 = *(const bf16x8*)(pw + 32);
    ch2 = *(const bf16x8*)(pw + 64);
    cxn = *(const f32x4*)(px);
  }
#pragma unroll
  for (int idx = 0; idx < 32; ++idx) {
    // prefetch next group (clamped tail)
    const int ni = (idx < 31) ? idx + 1 : 31;
    const unsigned short* pn = pw + (size_t)ni * 1536;
    bf16x8 nh0 = *(const bf16x8*)(pn);
    bf16x8 nh1 = *(const bf16x8*)(pn + 32);
    bf16x8 nh2 = *(const bf16x8*)(pn + 64);
    f32x4 nxn = *(const f32x4*)(px + ni * 16);
    // pin: prefetch loads above issued before the compute below
    __builtin_amdgcn_sched_barrier(0);

    f32x4 acc = cxn;                          // -0.5*|xm|^2 preloaded
    acc = __builtin_amdgcn_mfma_f32_16x16x32_bf16(ch0, rHf[0], acc, 0, 0, 0);
    acc = __builtin_amdgcn_mfma_f32_16x16x32_bf16(ch1, rHf[1], acc, 0, 0, 0);
    acc = __builtin_amdgcn_mfma_f32_16x16x32_bf16(ch2, rHf[2], acc, 0, 0, 0);
    // C/D: col(lane&15)=query row; row((lane>>4)*4+r)=candidate offset.
    const unsigned tag = clsbase | (unsigned)(127 - idx * 4);
#pragma unroll
    for (int r = 0; r < 4; ++r) {
      unsigned sb = __float_as_uint(acc[r]);
      sb ^= ((unsigned)((int)sb >> 31)) | 0x80000000u;
      unsigned key = (sb & 0xFFFFF000u) | (tag - (unsigned)r);
      // in-place parallel sorted-desc insert via med3 (reads pre-insert state)
#pragma unroll
      for (int j = LT - 1; j >= 1; --j)
        ls[j] = med3u(ls[j - 1], ls[j], key);
      ls[0] = umax32(ls[0], key);
    }
    // rotate buffers (free after full unroll: pure renaming)
    ch0 = nh0; ch1 = nh1; ch2 = nh2; cxn = nxn;
  }
  // dump per-lane sorted key lists: row pr, entries [cls*12 .. +12)
  {
    unsigned* dst = &sEnt[pr][cls * LT];
    *(uint4*)(dst + 0) = make_uint4(ls[0], ls[1], ls[2], ls[3]);
    *(uint4*)(dst + 4) = make_uint4(ls[4], ls[5], ls[6], ls[7]);
    *(uint4*)(dst + 8) = make_uint4(ls[8], ls[9], ls[10], ls[11]);
  }
  __syncthreads();

  // rank-count merge: wave w handles rows w*4..w*4+3; lane owns entries {lane+64c}.
  // Keys unique -> ranks 0..191 a permutation -> all 24 candbuf slots written.
#pragma unroll
  for (int rr = 0; rr < 4; ++rr) {
    const int row = w * 4 + rr;
    unsigned mine[3]; int rk[3] = {0, 0, 0};
#pragma unroll
    for (int c = 0; c < 3; ++c) mine[c] = sEnt[row][lane + 64 * c];
    for (int i4 = 0; i4 < NENT / 4; ++i4) {
      uint4 e = *(const uint4*)&sEnt[row][i4 * 4];
#pragma unroll
      for (int c = 0; c < 3; ++c) {
        rk[c] += (e.x > mine[c]) ? 1 : 0;
        rk[c] += (e.y > mine[c]) ? 1 : 0;
        rk[c] += (e.z > mine[c]) ? 1 : 0;
        rk[c] += (e.w > mine[c]) ? 1 : 0;
      }
    }
#pragma unroll
    for (int c = 0; c < 3; ++c) {
      if (rk[c] < TCAND) {
        unsigned low = mine[c] & 0x7FFu;
        int kcls = (int)(low >> 7);
        int loc = 127 - (int)(low & 127u);
        unsigned id = (unsigned)(hoff + (kcls >> 2) * 512 + (loc >> 4) * 64 +
                                 ((loc >> 2) & 3) * 16 + (kcls & 3) * 4 + (loc & 3));
        candbuf[(size_t)(b * NN + nbase + row) * 48 + half * 24 + rk[c]] = id;
      }
    }
  }
}

// ---------------- kernel 3: FUSED exact f64 top-20 + BN statistics ----------------
// 512 thr = 8 waves, 8 rows/block, grid PTS/8, XCD-swizzled (b=blk&3).
__global__ __launch_bounds__(512) void k_selstats(
    const unsigned* __restrict__ candbuf, const float* __restrict__ xT,
    const float* __restrict__ yG, const float* __restrict__ yC,
    int* __restrict__ idxout, double* __restrict__ stats) {
  __shared__ int sTop[8][KK];
  __shared__ float rs1[8][32], rs2[8][32];
  const int t = threadIdx.x, lane = t & 63, w = t >> 6;
  const int b = blockIdx.x & 3;
  const int n = (blockIdx.x >> 2) * 8 + w;
  const int row = b * NN + n;
  const unsigned* cp = candbuf + (size_t)row * 48;
  const int hf = lane & 1;
  unsigned long long k0, k1; int c0, c1;
#pragma unroll
  for (int pass = 0; pass < 2; ++pass) {
    const int ci = pass * 24 + ((lane < 48) ? (lane >> 1) : 23);
    const int mycand = (int)cp[ci];
    const float* xm = xT + ((size_t)b * NN + mycand) * CC + hf * 48;
    const float* xr = xT + ((size_t)b * NN + n) * CC + hf * 48;
    double dot = 0.0, m2 = 0.0;
#pragma unroll 4
    for (int j = 0; j < 12; ++j) {
      float4 a = *(const float4*)&xm[j * 4];
      float4 q = *(const float4*)&xr[j * 4];
      dot = fma((double)q.x, (double)a.x, dot); m2 = fma((double)a.x, (double)a.x, m2);
      dot = fma((double)q.y, (double)a.y, dot); m2 = fma((double)a.y, (double)a.y, m2);
      dot = fma((double)q.z, (double)a.z, dot); m2 = fma((double)a.z, (double)a.z, m2);
      dot = fma((double)q.w, (double)a.w, dot); m2 = fma((double)a.w, (double)a.w, m2);
    }
    dot += __shfl_xor(dot, 1);
    m2 += __shfl_xor(m2, 1);
    double sc = 2.0 * dot - m2;
    unsigned long long bits = (unsigned long long)__double_as_longlong(sc);
    bits ^= ((unsigned long long)((long long)bits >> 63)) | 0x8000000000000000ull;
    unsigned long long key = (bits & ~0xFFFull) | (unsigned long long)(4095 - mycand);
    if (pass == 0) { k0 = key; c0 = mycand; } else { k1 = key; c1 = mycand; }
  }
  int r0c = 0, r1c = 0;
#pragma unroll
  for (int j = 0; j < 24; ++j) {
    unsigned long long a = __shfl(k0, j * 2);
    unsigned long long bb = __shfl(k1, j * 2);
    r0c += (a > k0) ? 1 : 0; r0c += (bb > k0) ? 1 : 0;
    r1c += (a > k1) ? 1 : 0; r1c += (bb > k1) ? 1 : 0;
  }
  if (lane < 48 && hf == 0) {
    if (r0c < KK) { idxout[(size_t)row * KK + r0c] = c0; sTop[w][r0c] = c0; }
    if (r1c < KK) { idxout[(size_t)row * KK + r1c] = c1; sTop[w][r1c] = c1; }
  }
  __builtin_amdgcn_wave_barrier();  // same-wave LDS write->read fence (compile-time)

  // ---- phase B: norm statistics for this row ----
  const int o = lane & 31, kh = lane >> 5;
  const size_t cb = (size_t)row * 192 + o * 3;
  const float pc0 = yC[cb], pc1 = yC[cb + 1], pc2 = yC[cb + 2];
  float s1 = 0.f, s2 = 0.f;
#pragma unroll
  for (int j = 0; j < 10; ++j) {
    int m = sTop[w][2 * j + kh];
    size_t a = ((size_t)b * NN + m) * 192 + o * 3;
    float p0 = yG[a] + pc0, p1 = yG[a + 1] + pc1, p2 = yG[a + 2] + pc2;
    float nr = sqrtf(p0 * p0 + p1 * p1 + p2 * p2) + 1e-6f;
    s1 += nr; s2 = fmaf(nr, nr, s2);
  }
  s1 += __shfl_xor(s1, 32);
  s2 += __shfl_xor(s2, 32);
  if (lane < 32) { rs1[w][o] = s1; rs2[w][o] = s2; }
  __syncthreads();
  if (t < 32) {
    float a1 = 0.f, a2 = 0.f;
#pragma unroll
    for (int ww = 0; ww < 8; ++ww) { a1 += rs1[ww][t]; a2 += rs2[ww][t]; }
    atomicAdd(&stats[t], (double)a1);
    atomicAdd(&stats[32 + t], (double)a2);
  }
}

// ---------------- kernel 4: gather + activation + mean over k (BN inlined) ----------------
__global__ __launch_bounds__(256) void k_out(
    const float* __restrict__ yG, const float* __restrict__ yC,
    const int* __restrict__ idx, const double* __restrict__ stats,
    const float* __restrict__ gamma, const float* __restrict__ beta,
    float* __restrict__ out) {
  __shared__ float sS[64];
  const int t = threadIdx.x, o = t & 31, nl = t >> 5;
  if (t < 32) {
    const double M = (double)BB * NN * KK;
    double mean = stats[t] / M;
    double var = stats[32 + t] / M - mean * mean;
    double inv = 1.0 / sqrt(var + 1e-5);
    sS[t] = (float)((double)gamma[t] * inv);
    sS[32 + t] = (float)((double)beta[t] - mean * (double)gamma[t] * inv);
  }
  __syncthreads();
  const int b = blockIdx.x & 3;
  const int n = (blockIdx.x >> 2) * 8 + nl;
  const size_t cb = (size_t)(b * NN + n) * 192 + o * 3;
  const float pc0 = yC[cb], pc1 = yC[cb + 1], pc2 = yC[cb + 2];
  const float dc0 = yC[cb + 96], dc1 = yC[cb + 97], dc2 = yC[cb + 98];
  const float sc = sS[o], sh = sS[32 + o];
  const int* ip = idx + (size_t)(b * NN + n) * KK;
  float a0 = 0.f, a1 = 0.f, a2 = 0.f;
  for (int k = 0; k < KK; ++k) {
    int m = ip[k];
    size_t a = (size_t)(b * NN + m) * 192 + o * 3;
    float p0 = yG[a] + pc0, p1 = yG[a + 1] + pc1, p2 = yG[a + 2] + pc2;
    float d0 = yG[a + 96] + dc0, d1 = yG[a + 97] + dc1, d2 = yG[a + 98] + dc2;
    float nr = sqrtf(p0 * p0 + p1 * p1 + p2 * p2) + 1e-6f;
    float f = (sc * nr + sh) / nr;
    p0 *= f; p1 *= f; p2 *= f;
    float dt = p0 * d0 + p1 * d1 + p2 * d2;
    float w8 = (dt >= 0.f) ? 0.f : 0.8f * dt / (d0 * d0 + d1 * d1 + d2 * d2 + 1e-6f);
    a0 += p0 - w8 * d0; a1 += p1 - w8 * d1; a2 += p2 - w8 * d2;
  }
  const float inv = 1.f / (float)KK;
  const size_t ob = ((size_t)(b * OO + o) * 3) * NN + n;
  out[ob] = a0 * inv; out[ob + NN] = a1 * inv; out[ob + 2 * NN] = a2 * inv;
}

extern "C" void kernel_launch(void* const* d_in, const int* in_sizes, int n_in,
                              void* d_out, int out_size, void* d_ws, size_t ws_size,
                              hipStream_t stream) {
  (void)in_sizes; (void)n_in; (void)out_size;
  const float* x = (const float*)d_in[0];
  const float* Wf = (const float*)d_in[1];
  const float* Wd = (const float*)d_in[2];
  const float* gamma = (const float*)d_in[3];
  const float* beta = (const float*)d_in[4];
  float* out = (float*)d_out;

  char* ws = (char*)d_ws;
  size_t off = 0;
  auto alloc = [&](size_t bytes) -> void* {
    void* p = ws + off;
    off += (bytes + 255) & ~(size_t)255;
    return p;
  };
  float* yG = (float*)alloc((size_t)PTS * 192 * 4);
  float* yC = (float*)alloc((size_t)PTS * 192 * 4);
  float* xneg = (float*)alloc((size_t)PTS * 4);
  int* idx   = (int*)alloc((size_t)PTS * KK * 4);
  double* stats = (double*)alloc(64 * 8);
  unsigned short* hb16 = (unsigned short*)alloc((size_t)PTS * 96 * 2);
  float* xT  = (float*)alloc((size_t)PTS * CC * 4);
  unsigned* candbuf = (unsigned*)alloc((size_t)PTS * 48 * 4);
  if (ws_size < off) return;

  hipMemsetAsync(stats, 0, 64 * 8, stream);
  k_fp<<<dim3(PTS / 64), dim3(256), 0, stream>>>(x, Wf, Wd, yG, yC, xneg, hb16, xT);
  k_dist<<<dim3(BB * NN / 16 * 2), dim3(256), 0, stream>>>(hb16, xneg, candbuf);
  k_selstats<<<dim3(PTS / 8), dim3(512), 0, stream>>>(candbuf, xT, yG, yC, idx, stats);
  k_out<<<dim3(PTS / 8), dim3(256), 0, stream>>>(yG, yC, idx, stats, gamma, beta, out);
}